// Round 5
// baseline (171.305 us; speedup 1.0000x reference)
//
#include <hip/hip_runtime.h>
#include <hip/hip_bf16.h>

constexpr int B_  = 128;
constexpr int N_  = 512;
constexpr int F_  = 64;
constexpr int D_  = 128;
constexpr int E_  = 8192;
constexpr int BN_ = B_ * N_;              // 65536
constexpr float SLOPE = 0.2f;
constexpr float EPS_  = 1e-5f;
constexpr int OFF_PRED = BN_ * F_;        // 4194304 (elements)
constexpr int OFF_W    = OFF_PRED + BN_;  // 4259840

// workspace float-offsets (ws = 256 MiB per the fillBuffer WRITE_SIZE)
constexpr int WS_STATS = 16896;    // f[16][256]  bucketed (sum | sumsq), 4096 floats
constexpr int NBKT     = 16;
constexpr int WS_WLT   = 25860;    // u16[128n][64k]   (bf16 Wl^T)
constexpr int WS_WRT   = 29956;    // u16[64n][128k]   (bf16 Wr^T)
constexpr int WS_Y     = 34052;    // bf16[BN*64] = 8.4 MB (byte 136208, 16B aligned)

// scratch carved out of `out` (fully overwritten later by kD's recons):
//   XT bf16 [B][64 f][512 m]  at u16 offset 0
//   A  bf16 [512 n][512 m]    at u16 offset 4,194,304
constexpr int A_U16 = 4194304;

typedef __attribute__((ext_vector_type(8))) short bf16x8;
typedef __attribute__((ext_vector_type(4))) float f32x4;

__device__ __forceinline__ float lrelu(float w) { return w > 0.f ? w : SLOPE * w; }
__device__ __forceinline__ unsigned short f2b(float v) {
  __hip_bfloat16 h = __float2bfloat16(v);
  return *(unsigned short*)&h;
}
__device__ __forceinline__ float b2f(unsigned short u) {
  __hip_bfloat16 h = *(__hip_bfloat16*)&u;
  return __bfloat162float(h);
}

// K0: fused prep, grid 1088.
//   [   0, 256): XT[b][f][m] = bf16(X[b][m][f])  (block 0 zeros stat buckets)
//   [ 256, 288): wlT[n][k] = bf16(Wl[k][n])
//   [ 288, 320): wrT[n][k] = bf16(Wr[k][n])
//   [ 320, 576): W passthrough copy (float4)
//   [ 576,1088): dense softmax row build (one block per dst node)
__global__ __launch_bounds__(256) void k_prep(
    const float* __restrict__ X, const float* __restrict__ W,
    const float* __restrict__ Wl, const float* __restrict__ Wr,
    const int* __restrict__ ei,
    float* ws, unsigned short* __restrict__ outs, float* __restrict__ out)
{
  const int t = threadIdx.x;
  const int blk = blockIdx.x;
  if (blk < 256) {
    if (blk == 0) {
      #pragma unroll
      for (int i = 0; i < NBKT; i++) ws[WS_STATS + i * 256 + t] = 0.f;
    }
    const int b = blk >> 1;
    const int m = ((blk & 1) << 8) + t;
    const float* xrow = X + ((size_t)b * N_ + m) * F_;
    unsigned short* xtb = outs + (size_t)b * (F_ * N_);
    #pragma unroll
    for (int f4 = 0; f4 < 16; f4++) {
      float4 v = *(const float4*)(xrow + f4 * 4);
      xtb[(f4 * 4 + 0) * N_ + m] = f2b(v.x);
      xtb[(f4 * 4 + 1) * N_ + m] = f2b(v.y);
      xtb[(f4 * 4 + 2) * N_ + m] = f2b(v.z);
      xtb[(f4 * 4 + 3) * N_ + m] = f2b(v.w);
    }
  } else if (blk < 288) {
    unsigned short* wlT = (unsigned short*)(ws + WS_WLT);
    int i = (blk - 256) * 256 + t;            // [0, 8192)
    int n = i >> 6, k = i & 63;
    wlT[i] = f2b(Wl[k * D_ + n]);
  } else if (blk < 320) {
    unsigned short* wrT = (unsigned short*)(ws + WS_WRT);
    int i = (blk - 288) * 256 + t;            // [0, 8192)
    int n = i >> 7, k = i & 127;
    wrT[i] = f2b(Wr[k * F_ + n]);
  } else if (blk < 576) {
    int i = (blk - 320) * 256 + t;            // [0, 65536)
    ((float4*)(out + OFF_W))[i] = ((const float4*)W)[i];
  } else {
    // dense masked row softmax (exact duplicate handling: cnt * e^a)
    __shared__ unsigned cnt[N_];
    __shared__ float red[8];
    unsigned short* Abf = outs + A_U16;
    const int row = blk - 576;
    const int wv = t >> 6;
    cnt[t] = 0u; cnt[t + 256] = 0u;
    __syncthreads();
    for (int e = t; e < E_; e += 256) {
      int d = ei[E_ + e];
      if (d == row) atomicAdd(&cnt[ei[e]], 1u);
    }
    __syncthreads();
    const int s0 = t, s1 = t + 256;
    const float a0 = lrelu(W[row * N_ + s0]);
    const float a1 = lrelu(W[row * N_ + s1]);
    const unsigned c0 = cnt[s0] + (s0 == row ? 1u : 0u);
    const unsigned c1 = cnt[s1] + (s1 == row ? 1u : 0u);
    float m = fmaxf(c0 ? a0 : -3.4e38f, c1 ? a1 : -3.4e38f);
    #pragma unroll
    for (int off = 32; off; off >>= 1) m = fmaxf(m, __shfl_xor(m, off));
    if ((t & 63) == 0) red[wv] = m;
    __syncthreads();
    const float amax = fmaxf(fmaxf(red[0], red[1]), fmaxf(red[2], red[3]));
    const float e0 = c0 ? (float)c0 * __expf(a0 - amax) : 0.f;
    const float e1 = c1 ? (float)c1 * __expf(a1 - amax) : 0.f;
    float sm = e0 + e1;
    #pragma unroll
    for (int off = 32; off; off >>= 1) sm += __shfl_xor(sm, off);
    if ((t & 63) == 0) red[4 + wv] = sm;
    __syncthreads();
    const float inv = 1.f / (red[4] + red[5] + red[6] + red[7]);
    Abf[row * N_ + s0] = f2b(e0 * inv);
    Abf[row * N_ + s1] = f2b(e1 * inv);
  }
}

// K1: aggregation GEMM + BN stats only (no H materialization).
//   Y-tile (32n x 64f) = A-slice @ XT_b via MFMA -> global Y (bf16) + ys LDS
//   h-tile (32n x 128d) = Y @ Wl via MFMA, used ONLY for stat sums (discarded)
//   stats -> bucketed end-of-kernel atomics.
// grid = 2048: b = blk&127 (same-b blocks stride-128 => same XCD for XT reuse),
// ns = blk>>7 (16 slices of 32 rows). 4 waves; LDS = 4 KB.
__global__ __launch_bounds__(256) void kBC(
    const unsigned short* __restrict__ XT, float* ws)
{
  __shared__ __align__(16) unsigned short ys[32 * 64];    // Y tile, XOR-swizzled
  float* f = ws;
  unsigned short* Y = (unsigned short*)(ws + WS_Y);
  const unsigned short* wlT = (const unsigned short*)(ws + WS_WLT);
  const unsigned short* Abf = XT + A_U16;
  const int t = threadIdx.x;
  const int wv = t >> 6, lane = t & 63;
  const int m = lane & 15, quad = lane >> 4;
  const int b = blockIdx.x & 127, ns = blockIdx.x >> 7;
  const int n0 = ns * 32;

  // ---- Y GEMM: Y^T[f][n] = XT_b[f][:] . A[n][:]; wave wv = f-rows [16wv,16wv+16) ----
  const unsigned short* af = XT + (size_t)b * (F_ * N_) + (wv * 16 + m) * N_;
  f32x4 acc[2] = {{0.f,0.f,0.f,0.f},{0.f,0.f,0.f,0.f}};
  #pragma unroll 4
  for (int kk = 0; kk < 16; kk++) {
    const int k0 = kk * 32 + quad * 8;
    bf16x8 a = *(const bf16x8*)(af + k0);
    #pragma unroll
    for (int nt = 0; nt < 2; nt++) {
      bf16x8 bb = *(const bf16x8*)(Abf + (n0 + nt * 16 + m) * N_ + k0);
      acc[nt] = __builtin_amdgcn_mfma_f32_16x16x32_bf16(a, bb, acc[nt], 0, 0, 0);
    }
  }
  // global Y write (row = n0+nt*16+m, cols wv*16+quad*4..+3) + swizzled ys
  const size_t rb = (size_t)b * N_ + n0 + m;
  #pragma unroll
  for (int nt = 0; nt < 2; nt++) {
    ushort4 y4;
    y4.x = f2b(acc[nt][0]); y4.y = f2b(acc[nt][1]);
    y4.z = f2b(acc[nt][2]); y4.w = f2b(acc[nt][3]);
    *(ushort4*)(Y + (rb + nt * 16) * F_ + wv * 16 + quad * 4) = y4;
    const int n = nt * 16 + m;
    const int c = (wv * 16 + quad * 4) ^ ((n & 7) << 3);
    *(ushort4*)(ys + n * 64 + c) = y4;
  }
  __syncthreads();

  // ---- h GEMM (stats only): wave wv owns d0 = wv*32 ----
  const int d0 = wv * 32;
  bf16x8 bw00 = *(const bf16x8*)(wlT + (d0 + m) * 64 + quad * 8);
  bf16x8 bw01 = *(const bf16x8*)(wlT + (d0 + m) * 64 + 32 + quad * 8);
  bf16x8 bw10 = *(const bf16x8*)(wlT + (d0 + 16 + m) * 64 + quad * 8);
  bf16x8 bw11 = *(const bf16x8*)(wlT + (d0 + 16 + m) * 64 + 32 + quad * 8);
  f32x4 acch[2][2];
  #pragma unroll
  for (int nt = 0; nt < 2; nt++) {
    acch[nt][0] = f32x4{0.f,0.f,0.f,0.f};
    acch[nt][1] = f32x4{0.f,0.f,0.f,0.f};
  }
  #pragma unroll
  for (int nt = 0; nt < 2; nt++) {
    const int n2 = nt * 16 + m;
    const int sw = (n2 & 7) << 3;
    bf16x8 aA = *(const bf16x8*)(ys + n2 * 64 + ((quad * 8) ^ sw));
    bf16x8 aB = *(const bf16x8*)(ys + n2 * 64 + ((32 + quad * 8) ^ sw));
    acch[nt][0] = __builtin_amdgcn_mfma_f32_16x16x32_bf16(aA, bw00, acch[nt][0], 0, 0, 0);
    acch[nt][0] = __builtin_amdgcn_mfma_f32_16x16x32_bf16(aB, bw01, acch[nt][0], 0, 0, 0);
    acch[nt][1] = __builtin_amdgcn_mfma_f32_16x16x32_bf16(aA, bw10, acch[nt][1], 0, 0, 0);
    acch[nt][1] = __builtin_amdgcn_mfma_f32_16x16x32_bf16(aB, bw11, acch[nt][1], 0, 0, 0);
  }

  // ---- stat accumulation (registers) -> shuffle reduce -> bucketed atomics ----
  float sm0 = 0.f, sq0 = 0.f, sm1 = 0.f, sq1 = 0.f;
  #pragma unroll
  for (int nt = 0; nt < 2; nt++) {
    #pragma unroll
    for (int i = 0; i < 4; i++) {
      float v0 = acch[nt][0][i], v1 = acch[nt][1][i];
      sm0 += v0; sq0 += v0 * v0;
      sm1 += v1; sq1 += v1 * v1;
    }
  }
  sm0 += __shfl_xor(sm0, 16); sm0 += __shfl_xor(sm0, 32);
  sq0 += __shfl_xor(sq0, 16); sq0 += __shfl_xor(sq0, 32);
  sm1 += __shfl_xor(sm1, 16); sm1 += __shfl_xor(sm1, 32);
  sq1 += __shfl_xor(sq1, 16); sq1 += __shfl_xor(sq1, 32);
  if (quad == 0) {
    float* st = f + WS_STATS + (blockIdx.x & (NBKT - 1)) * 256;
    atomicAdd(&st[d0 + m], sm0);
    atomicAdd(&st[128 + d0 + m], sq0);
    atomicAdd(&st[d0 + 16 + m], sm1);
    atomicAdd(&st[128 + d0 + 16 + m], sq1);
  }
}

// K2: epilogue: read Y, h = Y@Wl (MFMA), BN+ReLU -> zs -> GEMM2 + pred head.
__global__ __launch_bounds__(256) void kD(
    const float* __restrict__ gamma, const float* __restrict__ beta,
    const float* __restrict__ br, const float* __restrict__ wp,
    const float* __restrict__ bp, float* ws, float* __restrict__ out)
{
  constexpr int LDP = 136;                        // zs row pad: breaks 256B stride
  __shared__ __align__(16) unsigned short zs[16 * LDP];
  __shared__ float rsL[D_], zbL[D_], wpL[D_];
  float* f = ws;
  const unsigned short* Yb  = (const unsigned short*)(f + WS_Y);
  const unsigned short* wlT = (const unsigned short*)(f + WS_WLT);
  const unsigned short* wrT = (const unsigned short*)(f + WS_WRT);
  const int t = threadIdx.x;
  const int wv = t >> 6, lane = t & 63;
  const int m = lane & 15, quad = lane >> 4;
  const size_t row0 = (size_t)blockIdx.x * 16;

  if (t < 128) {
    float s = 0.f, sq = 0.f;
    #pragma unroll
    for (int bk = 0; bk < NBKT; bk++) {
      s  += f[WS_STATS + bk * 256 + t];
      sq += f[WS_STATS + bk * 256 + 128 + t];
    }
    float mu  = s * (1.f / (float)BN_);
    float var = sq * (1.f / (float)BN_) - mu * mu;
    float rg  = rsqrtf(var + EPS_) * gamma[t];
    rsL[t] = rg;
    zbL[t] = beta[t] - mu * rg;
    wpL[t] = wp[t];
  }

  // ---- GEMM1: h tile [16 x 128], wave wv covers col-tiles 2wv, 2wv+1 ----
  const int T0 = 2 * wv, T1 = 2 * wv + 1;
  bf16x8 a0 = *(const bf16x8*)(Yb + (row0 + m) * 64 +  0 + quad * 8);
  bf16x8 a1 = *(const bf16x8*)(Yb + (row0 + m) * 64 + 32 + quad * 8);
  bf16x8 b00 = *(const bf16x8*)(wlT + (T0 * 16 + m) * 64 +  0 + quad * 8);
  bf16x8 b01 = *(const bf16x8*)(wlT + (T0 * 16 + m) * 64 + 32 + quad * 8);
  bf16x8 b10 = *(const bf16x8*)(wlT + (T1 * 16 + m) * 64 +  0 + quad * 8);
  bf16x8 b11 = *(const bf16x8*)(wlT + (T1 * 16 + m) * 64 + 32 + quad * 8);
  f32x4 acc0 = {0.f, 0.f, 0.f, 0.f}, acc1 = {0.f, 0.f, 0.f, 0.f};
  acc0 = __builtin_amdgcn_mfma_f32_16x16x32_bf16(a0, b00, acc0, 0, 0, 0);
  acc0 = __builtin_amdgcn_mfma_f32_16x16x32_bf16(a1, b01, acc0, 0, 0, 0);
  acc1 = __builtin_amdgcn_mfma_f32_16x16x32_bf16(a0, b10, acc1, 0, 0, 0);
  acc1 = __builtin_amdgcn_mfma_f32_16x16x32_bf16(a1, b11, acc1, 0, 0, 0);
  __syncthreads();   // rsL/zbL ready

  // ---- BN + ReLU -> zs (bf16) ----
  {
    int c0 = T0 * 16 + m, c1 = T1 * 16 + m;
    float rs0 = rsL[c0], be0 = zbL[c0];
    float rs1 = rsL[c1], be1 = zbL[c1];
    #pragma unroll
    for (int i = 0; i < 4; i++) {
      int row = quad * 4 + i;
      float z0 = fmaf(acc0[i], rs0, be0);
      float z1 = fmaf(acc1[i], rs1, be1);
      zs[row * LDP + c0] = f2b(z0 > 0.f ? z0 : 0.f);
      zs[row * LDP + c1] = f2b(z1 > 0.f ? z1 : 0.f);
    }
  }
  __syncthreads();

  // ---- GEMM2: recons tile [16 x 64], wave wv -> col-tile wv ----
  {
    const int col = wv * 16 + m;
    float bias = br[col];
    f32x4 acc2 = {bias, bias, bias, bias};
    #pragma unroll
    for (int s = 0; s < 4; s++) {
      bf16x8 az = *(const bf16x8*)(zs + m * LDP + s * 32 + quad * 8);
      bf16x8 bz = *(const bf16x8*)(wrT + col * D_ + s * 32 + quad * 8);
      acc2 = __builtin_amdgcn_mfma_f32_16x16x32_bf16(az, bz, acc2, 0, 0, 0);
    }
    #pragma unroll
    for (int i = 0; i < 4; i++)
      out[(row0 + quad * 4 + i) * F_ + col] = acc2[i];
  }

  // ---- pred head: 8 lanes per row, 16 d each, shuffle reduce ----
  if (t < 128) {
    const int r = t >> 3, j = t & 7;
    float a = 0.f;
    #pragma unroll
    for (int k = 0; k < 16; k++) {
      const int d = j * 16 + k;
      a += b2f(zs[r * LDP + d]) * wpL[d];
    }
    a += __shfl_xor(a, 1); a += __shfl_xor(a, 2); a += __shfl_xor(a, 4);
    if (j == 0) out[OFF_PRED + row0 + r] = a + bp[0];
  }
}

extern "C" void kernel_launch(void* const* d_in, const int* in_sizes, int n_in,
                              void* d_out, int out_size, void* d_ws, size_t ws_size,
                              hipStream_t stream) {
  const float* data  = (const float*)d_in[0];
  const int*   ei    = (const int*)d_in[1];
  const float* W     = (const float*)d_in[2];
  const float* lin_w = (const float*)d_in[3];
  // d_in[4] = gnn_bias: cancels exactly through training-mode BN
  const float* gamma = (const float*)d_in[5];
  const float* beta  = (const float*)d_in[6];
  const float* Wr    = (const float*)d_in[7];
  const float* br    = (const float*)d_in[8];
  const float* wp    = (const float*)d_in[9];
  const float* bp    = (const float*)d_in[10];
  float* out = (float*)d_out;
  float* ws  = (float*)d_ws;
  unsigned short* outs = (unsigned short*)d_out;   // XT @0, A @A_U16 (scratch)

  k_prep <<<1088,      256, 0, stream>>>(data, W, lin_w, Wr, ei, ws, outs, out);
  kBC    <<<2048,      256, 0, stream>>>(outs, ws);
  kD     <<<BN_ / 16,  256, 0, stream>>>(gamma, beta, br, wp, bp, ws, out);
}

// Round 7
// 148.503 us; speedup vs baseline: 1.1535x; 1.1535x over previous
//
#include <hip/hip_runtime.h>
#include <hip/hip_bf16.h>

constexpr int B_  = 128;
constexpr int N_  = 512;
constexpr int F_  = 64;
constexpr int D_  = 128;
constexpr int E_  = 8192;
constexpr int BN_ = B_ * N_;              // 65536
constexpr float SLOPE = 0.2f;
constexpr float EPS_  = 1e-5f;
constexpr int OFF_PRED = BN_ * F_;        // 4194304 (elements)
constexpr int OFF_W    = OFF_PRED + BN_;  // 4259840

// workspace float-offsets (ws = 256 MiB per the fillBuffer WRITE_SIZE)
constexpr int WS_STATS = 16896;    // f[16][256]  bucketed (sum | sumsq), 4096 floats
constexpr int NBKT     = 16;
constexpr int WS_WLT   = 25860;    // u16[128n][64k]   (bf16 Wl^T)
constexpr int WS_WRT   = 29956;    // u16[64n][128k]   (bf16 Wr^T)
constexpr int WS_Y     = 34052;    // bf16[BN*64] = 8.4 MB (byte 136208, 16B aligned)

// scratch carved out of `out` (fully overwritten later by kD's recons).
// Row strides PADDED to 544 u16 (1088 B): rows shift one 64B line each, so the
// 16-row gathers in kBC spread over 16 L2 channels instead of camping on 1-2
// (1 KB stride varies only addr bit >=10 -> channel conflict).
//   XT bf16 [B][64 f][544]   at u16 offset 0          (4,456,448 u16)
//   A  bf16 [512 n][544]     at u16 offset 4,456,448  (  278,528 u16)
// ends at byte 9,469,952 < OFF_PRED bytes (16,777,216).
constexpr int XTP   = 544;
constexpr int AP    = 544;
constexpr int A_U16 = B_ * F_ * XTP;      // 4,456,448

typedef __attribute__((ext_vector_type(8))) short bf16x8;
typedef __attribute__((ext_vector_type(4))) float f32x4;

__device__ __forceinline__ float lrelu(float w) { return w > 0.f ? w : SLOPE * w; }
__device__ __forceinline__ unsigned short f2b(float v) {
  __hip_bfloat16 h = __float2bfloat16(v);
  return *(unsigned short*)&h;
}
__device__ __forceinline__ float b2f(unsigned short u) {
  __hip_bfloat16 h = *(__hip_bfloat16*)&u;
  return __bfloat162float(h);
}

// K0: fused prep, grid 1088.
//   [   0, 256): XT[b][f][m] = bf16(X[b][m][f])  (block 0 zeros stat buckets)
//   [ 256, 288): wlT[n][k] = bf16(Wl[k][n])
//   [ 288, 320): wrT[n][k] = bf16(Wr[k][n])
//   [ 320, 576): W passthrough copy (float4)
//   [ 576,1088): dense softmax row build (one block per dst node)
__global__ __launch_bounds__(256) void k_prep(
    const float* __restrict__ X, const float* __restrict__ W,
    const float* __restrict__ Wl, const float* __restrict__ Wr,
    const int* __restrict__ ei,
    float* ws, unsigned short* __restrict__ outs, float* __restrict__ out)
{
  const int t = threadIdx.x;
  const int blk = blockIdx.x;
  if (blk < 256) {
    if (blk == 0) {
      #pragma unroll
      for (int i = 0; i < NBKT; i++) ws[WS_STATS + i * 256 + t] = 0.f;
    }
    const int b = blk >> 1;
    const int m = ((blk & 1) << 8) + t;
    const float* xrow = X + ((size_t)b * N_ + m) * F_;
    unsigned short* xtb = outs + (size_t)b * (F_ * XTP);
    #pragma unroll
    for (int f4 = 0; f4 < 16; f4++) {
      float4 v = *(const float4*)(xrow + f4 * 4);
      xtb[(f4 * 4 + 0) * XTP + m] = f2b(v.x);
      xtb[(f4 * 4 + 1) * XTP + m] = f2b(v.y);
      xtb[(f4 * 4 + 2) * XTP + m] = f2b(v.z);
      xtb[(f4 * 4 + 3) * XTP + m] = f2b(v.w);
    }
  } else if (blk < 288) {
    unsigned short* wlT = (unsigned short*)(ws + WS_WLT);
    int i = (blk - 256) * 256 + t;            // [0, 8192)
    int n = i >> 6, k = i & 63;
    wlT[i] = f2b(Wl[k * D_ + n]);
  } else if (blk < 320) {
    unsigned short* wrT = (unsigned short*)(ws + WS_WRT);
    int i = (blk - 288) * 256 + t;            // [0, 8192)
    int n = i >> 7, k = i & 127;
    wrT[i] = f2b(Wr[k * F_ + n]);
  } else if (blk < 576) {
    int i = (blk - 320) * 256 + t;            // [0, 65536)
    ((float4*)(out + OFF_W))[i] = ((const float4*)W)[i];
  } else {
    // dense masked row softmax (exact duplicate handling: cnt * e^a)
    __shared__ unsigned cnt[N_];
    __shared__ float red[8];
    unsigned short* Abf = outs + A_U16;
    const int row = blk - 576;
    const int wv = t >> 6;
    cnt[t] = 0u; cnt[t + 256] = 0u;
    __syncthreads();
    for (int e = t; e < E_; e += 256) {
      int d = ei[E_ + e];
      if (d == row) atomicAdd(&cnt[ei[e]], 1u);
    }
    __syncthreads();
    const int s0 = t, s1 = t + 256;
    const float a0 = lrelu(W[row * N_ + s0]);
    const float a1 = lrelu(W[row * N_ + s1]);
    const unsigned c0 = cnt[s0] + (s0 == row ? 1u : 0u);
    const unsigned c1 = cnt[s1] + (s1 == row ? 1u : 0u);
    float m = fmaxf(c0 ? a0 : -3.4e38f, c1 ? a1 : -3.4e38f);
    #pragma unroll
    for (int off = 32; off; off >>= 1) m = fmaxf(m, __shfl_xor(m, off));
    if ((t & 63) == 0) red[wv] = m;
    __syncthreads();
    const float amax = fmaxf(fmaxf(red[0], red[1]), fmaxf(red[2], red[3]));
    const float e0 = c0 ? (float)c0 * __expf(a0 - amax) : 0.f;
    const float e1 = c1 ? (float)c1 * __expf(a1 - amax) : 0.f;
    float sm = e0 + e1;
    #pragma unroll
    for (int off = 32; off; off >>= 1) sm += __shfl_xor(sm, off);
    if ((t & 63) == 0) red[4 + wv] = sm;
    __syncthreads();
    const float inv = 1.f / (red[4] + red[5] + red[6] + red[7]);
    Abf[row * AP + s0] = f2b(e0 * inv);
    Abf[row * AP + s1] = f2b(e1 * inv);
  }
}

// K1: aggregation GEMM + BN stats (round-4 structure + channel-pad + XCD swizzle).
//   Y-tile (64n x 64f) = A-slice @ XT_b via MFMA -> global Y (bf16) + ys LDS
//   h-tile (64n x 128d) = Y @ Wl via MFMA, used ONLY for stat sums (discarded)
//   stats -> bucketed end-of-kernel atomics.
// grid = 1024: b = blk&127 (blocks sharing XT_b sit stride-128 => same XCD),
// ns = blk>>7 (8 slices of 64 rows). 4 waves; LDS = 8 KB.
__global__ __launch_bounds__(256, 4) void kBC(
    const unsigned short* __restrict__ XT, float* ws)
{
  __shared__ __align__(16) unsigned short ys[64 * 64];    // Y tile, XOR-swizzled
  float* f = ws;
  unsigned short* Y = (unsigned short*)(ws + WS_Y);
  const unsigned short* wlT = (const unsigned short*)(ws + WS_WLT);
  const unsigned short* Abf = XT + A_U16;
  const int t = threadIdx.x;
  const int wv = t >> 6, lane = t & 63;
  const int m = lane & 15, quad = lane >> 4;
  const int b = blockIdx.x & 127, ns = blockIdx.x >> 7;   // ns in [0,8)
  const int n0 = ns * 64;

  // ---- Y GEMM: Y^T[f][n] = XT_b[f][:] . A[n][:]; wave wv = f-rows [16wv,16wv+16) ----
  const unsigned short* af = XT + (size_t)b * (F_ * XTP) + (wv * 16 + m) * XTP;
  f32x4 acc[4] = {{0.f,0.f,0.f,0.f},{0.f,0.f,0.f,0.f},
                  {0.f,0.f,0.f,0.f},{0.f,0.f,0.f,0.f}};
  #pragma unroll 4
  for (int kk = 0; kk < 16; kk++) {
    const int k0 = kk * 32 + quad * 8;
    bf16x8 a = *(const bf16x8*)(af + k0);
    #pragma unroll
    for (int nt = 0; nt < 4; nt++) {
      bf16x8 bb = *(const bf16x8*)(Abf + (n0 + nt * 16 + m) * AP + k0);
      acc[nt] = __builtin_amdgcn_mfma_f32_16x16x32_bf16(a, bb, acc[nt], 0, 0, 0);
    }
  }
  // global Y write (row = n0+nt*16+m, cols wv*16+quad*4..+3) + swizzled ys
  const size_t rb = (size_t)b * N_ + n0 + m;
  #pragma unroll
  for (int nt = 0; nt < 4; nt++) {
    ushort4 y4;
    y4.x = f2b(acc[nt][0]); y4.y = f2b(acc[nt][1]);
    y4.z = f2b(acc[nt][2]); y4.w = f2b(acc[nt][3]);
    *(ushort4*)(Y + (rb + nt * 16) * F_ + wv * 16 + quad * 4) = y4;
    const int n = nt * 16 + m;
    const int c = (wv * 16 + quad * 4) ^ ((n & 7) << 3);
    *(ushort4*)(ys + n * 64 + c) = y4;
  }
  __syncthreads();

  // ---- h GEMM (stats only): wave wv owns d0 = wv*32 ----
  const int d0 = wv * 32;
  bf16x8 bw00 = *(const bf16x8*)(wlT + (d0 + m) * 64 + quad * 8);
  bf16x8 bw01 = *(const bf16x8*)(wlT + (d0 + m) * 64 + 32 + quad * 8);
  bf16x8 bw10 = *(const bf16x8*)(wlT + (d0 + 16 + m) * 64 + quad * 8);
  bf16x8 bw11 = *(const bf16x8*)(wlT + (d0 + 16 + m) * 64 + 32 + quad * 8);
  f32x4 acch[4][2];
  #pragma unroll
  for (int nt = 0; nt < 4; nt++) {
    acch[nt][0] = f32x4{0.f,0.f,0.f,0.f};
    acch[nt][1] = f32x4{0.f,0.f,0.f,0.f};
  }
  #pragma unroll
  for (int nt = 0; nt < 4; nt++) {
    const int n2 = nt * 16 + m;
    const int sw = (n2 & 7) << 3;
    bf16x8 aA = *(const bf16x8*)(ys + n2 * 64 + ((quad * 8) ^ sw));
    bf16x8 aB = *(const bf16x8*)(ys + n2 * 64 + ((32 + quad * 8) ^ sw));
    acch[nt][0] = __builtin_amdgcn_mfma_f32_16x16x32_bf16(aA, bw00, acch[nt][0], 0, 0, 0);
    acch[nt][0] = __builtin_amdgcn_mfma_f32_16x16x32_bf16(aB, bw01, acch[nt][0], 0, 0, 0);
    acch[nt][1] = __builtin_amdgcn_mfma_f32_16x16x32_bf16(aA, bw10, acch[nt][1], 0, 0, 0);
    acch[nt][1] = __builtin_amdgcn_mfma_f32_16x16x32_bf16(aB, bw11, acch[nt][1], 0, 0, 0);
  }

  // ---- stat accumulation (registers) -> shuffle reduce -> bucketed atomics ----
  float sm0 = 0.f, sq0 = 0.f, sm1 = 0.f, sq1 = 0.f;
  #pragma unroll
  for (int nt = 0; nt < 4; nt++) {
    #pragma unroll
    for (int i = 0; i < 4; i++) {
      float v0 = acch[nt][0][i], v1 = acch[nt][1][i];
      sm0 += v0; sq0 += v0 * v0;
      sm1 += v1; sq1 += v1 * v1;
    }
  }
  sm0 += __shfl_xor(sm0, 16); sm0 += __shfl_xor(sm0, 32);
  sq0 += __shfl_xor(sq0, 16); sq0 += __shfl_xor(sq0, 32);
  sm1 += __shfl_xor(sm1, 16); sm1 += __shfl_xor(sm1, 32);
  sq1 += __shfl_xor(sq1, 16); sq1 += __shfl_xor(sq1, 32);
  if (quad == 0) {
    float* st = f + WS_STATS + (blockIdx.x & (NBKT - 1)) * 256;
    atomicAdd(&st[d0 + m], sm0);
    atomicAdd(&st[128 + d0 + m], sq0);
    atomicAdd(&st[d0 + 16 + m], sm1);
    atomicAdd(&st[128 + d0 + 16 + m], sq1);
  }
}

// K2: epilogue: read Y, h = Y@Wl (MFMA), BN+ReLU -> zs -> GEMM2 + pred head.
__global__ __launch_bounds__(256) void kD(
    const float* __restrict__ gamma, const float* __restrict__ beta,
    const float* __restrict__ br, const float* __restrict__ wp,
    const float* __restrict__ bp, float* ws, float* __restrict__ out)
{
  constexpr int LDP = 136;                        // zs row pad: breaks 256B stride
  __shared__ __align__(16) unsigned short zs[16 * LDP];
  __shared__ float rsL[D_], zbL[D_], wpL[D_];
  float* f = ws;
  const unsigned short* Yb  = (const unsigned short*)(f + WS_Y);
  const unsigned short* wlT = (const unsigned short*)(f + WS_WLT);
  const unsigned short* wrT = (const unsigned short*)(f + WS_WRT);
  const int t = threadIdx.x;
  const int wv = t >> 6, lane = t & 63;
  const int m = lane & 15, quad = lane >> 4;
  const size_t row0 = (size_t)blockIdx.x * 16;

  if (t < 128) {
    float s = 0.f, sq = 0.f;
    #pragma unroll
    for (int bk = 0; bk < NBKT; bk++) {
      s  += f[WS_STATS + bk * 256 + t];
      sq += f[WS_STATS + bk * 256 + 128 + t];
    }
    float mu  = s * (1.f / (float)BN_);
    float var = sq * (1.f / (float)BN_) - mu * mu;
    float rg  = rsqrtf(var + EPS_) * gamma[t];
    rsL[t] = rg;
    zbL[t] = beta[t] - mu * rg;
    wpL[t] = wp[t];
  }

  // ---- GEMM1: h tile [16 x 128], wave wv covers col-tiles 2wv, 2wv+1 ----
  const int T0 = 2 * wv, T1 = 2 * wv + 1;
  bf16x8 a0 = *(const bf16x8*)(Yb + (row0 + m) * 64 +  0 + quad * 8);
  bf16x8 a1 = *(const bf16x8*)(Yb + (row0 + m) * 64 + 32 + quad * 8);
  bf16x8 b00 = *(const bf16x8*)(wlT + (T0 * 16 + m) * 64 +  0 + quad * 8);
  bf16x8 b01 = *(const bf16x8*)(wlT + (T0 * 16 + m) * 64 + 32 + quad * 8);
  bf16x8 b10 = *(const bf16x8*)(wlT + (T1 * 16 + m) * 64 +  0 + quad * 8);
  bf16x8 b11 = *(const bf16x8*)(wlT + (T1 * 16 + m) * 64 + 32 + quad * 8);
  f32x4 acc0 = {0.f, 0.f, 0.f, 0.f}, acc1 = {0.f, 0.f, 0.f, 0.f};
  acc0 = __builtin_amdgcn_mfma_f32_16x16x32_bf16(a0, b00, acc0, 0, 0, 0);
  acc0 = __builtin_amdgcn_mfma_f32_16x16x32_bf16(a1, b01, acc0, 0, 0, 0);
  acc1 = __builtin_amdgcn_mfma_f32_16x16x32_bf16(a0, b10, acc1, 0, 0, 0);
  acc1 = __builtin_amdgcn_mfma_f32_16x16x32_bf16(a1, b11, acc1, 0, 0, 0);
  __syncthreads();   // rsL/zbL ready

  // ---- BN + ReLU -> zs (bf16) ----
  {
    int c0 = T0 * 16 + m, c1 = T1 * 16 + m;
    float rs0 = rsL[c0], be0 = zbL[c0];
    float rs1 = rsL[c1], be1 = zbL[c1];
    #pragma unroll
    for (int i = 0; i < 4; i++) {
      int row = quad * 4 + i;
      float z0 = fmaf(acc0[i], rs0, be0);
      float z1 = fmaf(acc1[i], rs1, be1);
      zs[row * LDP + c0] = f2b(z0 > 0.f ? z0 : 0.f);
      zs[row * LDP + c1] = f2b(z1 > 0.f ? z1 : 0.f);
    }
  }
  __syncthreads();

  // ---- GEMM2: recons tile [16 x 64], wave wv -> col-tile wv ----
  {
    const int col = wv * 16 + m;
    float bias = br[col];
    f32x4 acc2 = {bias, bias, bias, bias};
    #pragma unroll
    for (int s = 0; s < 4; s++) {
      bf16x8 az = *(const bf16x8*)(zs + m * LDP + s * 32 + quad * 8);
      bf16x8 bz = *(const bf16x8*)(wrT + col * D_ + s * 32 + quad * 8);
      acc2 = __builtin_amdgcn_mfma_f32_16x16x32_bf16(az, bz, acc2, 0, 0, 0);
    }
    #pragma unroll
    for (int i = 0; i < 4; i++)
      out[(row0 + quad * 4 + i) * F_ + col] = acc2[i];
  }

  // ---- pred head: 8 lanes per row, 16 d each, shuffle reduce ----
  if (t < 128) {
    const int r = t >> 3, j = t & 7;
    float a = 0.f;
    #pragma unroll
    for (int k = 0; k < 16; k++) {
      const int d = j * 16 + k;
      a += b2f(zs[r * LDP + d]) * wpL[d];
    }
    a += __shfl_xor(a, 1); a += __shfl_xor(a, 2); a += __shfl_xor(a, 4);
    if (j == 0) out[OFF_PRED + row0 + r] = a + bp[0];
  }
}

extern "C" void kernel_launch(void* const* d_in, const int* in_sizes, int n_in,
                              void* d_out, int out_size, void* d_ws, size_t ws_size,
                              hipStream_t stream) {
  const float* data  = (const float*)d_in[0];
  const int*   ei    = (const int*)d_in[1];
  const float* W     = (const float*)d_in[2];
  const float* lin_w = (const float*)d_in[3];
  // d_in[4] = gnn_bias: cancels exactly through training-mode BN
  const float* gamma = (const float*)d_in[5];
  const float* beta  = (const float*)d_in[6];
  const float* Wr    = (const float*)d_in[7];
  const float* br    = (const float*)d_in[8];
  const float* wp    = (const float*)d_in[9];
  const float* bp    = (const float*)d_in[10];
  float* out = (float*)d_out;
  float* ws  = (float*)d_ws;
  unsigned short* outs = (unsigned short*)d_out;   // XT @0, A @A_U16 (scratch)

  k_prep <<<1088,      256, 0, stream>>>(data, W, lin_w, Wr, ei, ws, outs, out);
  kBC    <<<1024,      256, 0, stream>>>(outs, ws);
  kD     <<<BN_ / 16,  256, 0, stream>>>(gamma, beta, br, wp, bp, ws, out);
}

// Round 8
// 140.081 us; speedup vs baseline: 1.2229x; 1.0601x over previous
//
#include <hip/hip_runtime.h>
#include <hip/hip_bf16.h>

constexpr int B_  = 128;
constexpr int N_  = 512;
constexpr int F_  = 64;
constexpr int D_  = 128;
constexpr int E_  = 8192;
constexpr int BN_ = B_ * N_;              // 65536
constexpr float SLOPE = 0.2f;
constexpr float EPS_  = 1e-5f;
constexpr int OFF_PRED = BN_ * F_;        // 4194304 (elements)
constexpr int OFF_W    = OFF_PRED + BN_;  // 4259840

// workspace float-offsets (ws = 256 MiB per the fillBuffer WRITE_SIZE)
constexpr int WS_STATS = 16896;    // f[16][256]  bucketed (sum | sumsq), 4096 floats
constexpr int NBKT     = 16;
constexpr int WS_WLT   = 25860;    // u16[128n][64k]   (bf16 Wl^T)
constexpr int WS_WRT   = 29956;    // u16[64n][128k]   (bf16 Wr^T)
constexpr int WS_H     = 34052;    // bf16[BN*128] = 16.7 MB (byte 136208, 16B aligned)

// scratch carved out of `out` (fully overwritten later by kD's recons).
// Row strides PADDED to 544 u16 (1088 B): rows shift one 64B line each, so the
// 16-row gathers in kBC spread over 16 L2 channels instead of camping on 1-2.
constexpr int XTP   = 544;
constexpr int AP    = 544;
constexpr int A_U16 = B_ * F_ * XTP;      // 4,456,448

typedef __attribute__((ext_vector_type(8))) short bf16x8;
typedef __attribute__((ext_vector_type(4))) float f32x4;

__device__ __forceinline__ float lrelu(float w) { return w > 0.f ? w : SLOPE * w; }
__device__ __forceinline__ unsigned short f2b(float v) {
  __hip_bfloat16 h = __float2bfloat16(v);
  return *(unsigned short*)&h;
}
__device__ __forceinline__ float b2f(unsigned short u) {
  __hip_bfloat16 h = *(__hip_bfloat16*)&u;
  return __bfloat162float(h);
}

// K0: fused prep, grid 1856.
//   [   0,1024): XT[b][f][m] = bf16(X[b][m][f])  (block 0 zeros stat buckets)
//   [1024,1056): wlT[n][k] = bf16(Wl[k][n])
//   [1056,1088): wrT[n][k] = bf16(Wr[k][n])
//   [1088,1344): W passthrough copy (float4)
//   [1344,1856): dense softmax row build (one block per dst node)
__global__ __launch_bounds__(256) void k_prep(
    const float* __restrict__ X, const float* __restrict__ W,
    const float* __restrict__ Wl, const float* __restrict__ Wr,
    const int* __restrict__ ei,
    float* ws, unsigned short* __restrict__ outs, float* __restrict__ out)
{
  const int t = threadIdx.x;
  const int blk = blockIdx.x;
  if (blk < 1024) {
    if (blk == 0) {
      #pragma unroll
      for (int i = 0; i < NBKT; i++) ws[WS_STATS + i * 256 + t] = 0.f;
    }
    const int b  = blk >> 3;
    const int mh = blk & 1, fh = (blk >> 1) & 3;
    const int m  = (mh << 8) + t;
    const float* xrow = X + ((size_t)b * N_ + m) * F_ + fh * 16;
    unsigned short* xtb = outs + (size_t)b * (F_ * XTP) + fh * 16 * XTP;
    #pragma unroll
    for (int f4 = 0; f4 < 4; f4++) {
      float4 v = *(const float4*)(xrow + f4 * 4);
      xtb[(f4 * 4 + 0) * XTP + m] = f2b(v.x);
      xtb[(f4 * 4 + 1) * XTP + m] = f2b(v.y);
      xtb[(f4 * 4 + 2) * XTP + m] = f2b(v.z);
      xtb[(f4 * 4 + 3) * XTP + m] = f2b(v.w);
    }
  } else if (blk < 1056) {
    unsigned short* wlT = (unsigned short*)(ws + WS_WLT);
    int i = (blk - 1024) * 256 + t;           // [0, 8192)
    int n = i >> 6, k = i & 63;
    wlT[i] = f2b(Wl[k * D_ + n]);
  } else if (blk < 1088) {
    unsigned short* wrT = (unsigned short*)(ws + WS_WRT);
    int i = (blk - 1056) * 256 + t;           // [0, 8192)
    int n = i >> 7, k = i & 127;
    wrT[i] = f2b(Wr[k * F_ + n]);
  } else if (blk < 1344) {
    int i = (blk - 1088) * 256 + t;           // [0, 65536)
    ((float4*)(out + OFF_W))[i] = ((const float4*)W)[i];
  } else {
    // dense masked row softmax (exact duplicate handling: cnt * e^a)
    __shared__ unsigned cnt[N_];
    __shared__ float red[8];
    unsigned short* Abf = outs + A_U16;
    const int row = blk - 1344;
    const int wv = t >> 6;
    cnt[t] = 0u; cnt[t + 256] = 0u;
    __syncthreads();
    for (int e = t; e < E_; e += 256) {
      int d = ei[E_ + e];
      if (d == row) atomicAdd(&cnt[ei[e]], 1u);
    }
    __syncthreads();
    const int s0 = t, s1 = t + 256;
    const float a0 = lrelu(W[row * N_ + s0]);
    const float a1 = lrelu(W[row * N_ + s1]);
    const unsigned c0 = cnt[s0] + (s0 == row ? 1u : 0u);
    const unsigned c1 = cnt[s1] + (s1 == row ? 1u : 0u);
    float m = fmaxf(c0 ? a0 : -3.4e38f, c1 ? a1 : -3.4e38f);
    #pragma unroll
    for (int off = 32; off; off >>= 1) m = fmaxf(m, __shfl_xor(m, off));
    if ((t & 63) == 0) red[wv] = m;
    __syncthreads();
    const float amax = fmaxf(fmaxf(red[0], red[1]), fmaxf(red[2], red[3]));
    const float e0 = c0 ? (float)c0 * __expf(a0 - amax) : 0.f;
    const float e1 = c1 ? (float)c1 * __expf(a1 - amax) : 0.f;
    float sm = e0 + e1;
    #pragma unroll
    for (int off = 32; off; off >>= 1) sm += __shfl_xor(sm, off);
    if ((t & 63) == 0) red[4 + wv] = sm;
    __syncthreads();
    const float inv = 1.f / (red[4] + red[5] + red[6] + red[7]);
    Abf[row * AP + s0] = f2b(e0 * inv);
    Abf[row * AP + s1] = f2b(e1 * inv);
  }
}

// K1: aggregation + projection + BN stats; writes H (bf16) directly.
//   Y-tile (64n x 64f) = A-slice @ XT_b via MFMA -> swizzled ys LDS
//   h-tile (64n x 128d) = Y @ Wl via MFMA -> H global (from registers)
//   stats -> bucketed end-of-kernel atomics.
// grid = 1024: b = blk&127 (blocks sharing XT_b sit stride-128 => same XCD),
// ns = blk>>7 (8 slices of 64 rows). 4 waves; LDS = 8 KB.
__global__ __launch_bounds__(256, 4) void kBC(
    const unsigned short* __restrict__ XT, float* ws)
{
  __shared__ __align__(16) unsigned short ys[64 * 64];    // Y tile, XOR-swizzled
  float* f = ws;
  unsigned short* H = (unsigned short*)(ws + WS_H);
  const unsigned short* wlT = (const unsigned short*)(ws + WS_WLT);
  const unsigned short* Abf = XT + A_U16;
  const int t = threadIdx.x;
  const int wv = t >> 6, lane = t & 63;
  const int m = lane & 15, quad = lane >> 4;
  const int b = blockIdx.x & 127, ns = blockIdx.x >> 7;   // ns in [0,8)
  const int n0 = ns * 64;

  // ---- Y GEMM: Y^T[f][n] = XT_b[f][:] . A[n][:]; wave wv = f-rows [16wv,16wv+16) ----
  const unsigned short* af = XT + (size_t)b * (F_ * XTP) + (wv * 16 + m) * XTP;
  f32x4 acc[4] = {{0.f,0.f,0.f,0.f},{0.f,0.f,0.f,0.f},
                  {0.f,0.f,0.f,0.f},{0.f,0.f,0.f,0.f}};
  #pragma unroll 4
  for (int kk = 0; kk < 16; kk++) {
    const int k0 = kk * 32 + quad * 8;
    bf16x8 a = *(const bf16x8*)(af + k0);
    #pragma unroll
    for (int nt = 0; nt < 4; nt++) {
      bf16x8 bb = *(const bf16x8*)(Abf + (n0 + nt * 16 + m) * AP + k0);
      acc[nt] = __builtin_amdgcn_mfma_f32_16x16x32_bf16(a, bb, acc[nt], 0, 0, 0);
    }
  }
  // Y tile -> swizzled ys only (no global Y)
  #pragma unroll
  for (int nt = 0; nt < 4; nt++) {
    const int n = nt * 16 + m;
    const int c = (wv * 16 + quad * 4) ^ ((n & 7) << 3);
    ushort4 y4;
    y4.x = f2b(acc[nt][0]); y4.y = f2b(acc[nt][1]);
    y4.z = f2b(acc[nt][2]); y4.w = f2b(acc[nt][3]);
    *(ushort4*)(ys + n * 64 + c) = y4;
  }
  __syncthreads();

  // ---- h GEMM: wave wv owns d0 = wv*32 ----
  const int d0 = wv * 32;
  bf16x8 bw00 = *(const bf16x8*)(wlT + (d0 + m) * 64 + quad * 8);
  bf16x8 bw01 = *(const bf16x8*)(wlT + (d0 + m) * 64 + 32 + quad * 8);
  bf16x8 bw10 = *(const bf16x8*)(wlT + (d0 + 16 + m) * 64 + quad * 8);
  bf16x8 bw11 = *(const bf16x8*)(wlT + (d0 + 16 + m) * 64 + 32 + quad * 8);
  f32x4 acch[4][2];
  #pragma unroll
  for (int nt = 0; nt < 4; nt++) {
    acch[nt][0] = f32x4{0.f,0.f,0.f,0.f};
    acch[nt][1] = f32x4{0.f,0.f,0.f,0.f};
  }
  #pragma unroll
  for (int nt = 0; nt < 4; nt++) {
    const int n2 = nt * 16 + m;
    const int sw = (n2 & 7) << 3;
    bf16x8 aA = *(const bf16x8*)(ys + n2 * 64 + ((quad * 8) ^ sw));
    bf16x8 aB = *(const bf16x8*)(ys + n2 * 64 + ((32 + quad * 8) ^ sw));
    acch[nt][0] = __builtin_amdgcn_mfma_f32_16x16x32_bf16(aA, bw00, acch[nt][0], 0, 0, 0);
    acch[nt][0] = __builtin_amdgcn_mfma_f32_16x16x32_bf16(aB, bw01, acch[nt][0], 0, 0, 0);
    acch[nt][1] = __builtin_amdgcn_mfma_f32_16x16x32_bf16(aA, bw10, acch[nt][1], 0, 0, 0);
    acch[nt][1] = __builtin_amdgcn_mfma_f32_16x16x32_bf16(aB, bw11, acch[nt][1], 0, 0, 0);
  }

  // ---- H store (bf16, 32B-contiguous per quarter-wave) + stat accumulation ----
  unsigned short* Hb = H + ((size_t)b * N_ + n0) * D_;
  float sm0 = 0.f, sq0 = 0.f, sm1 = 0.f, sq1 = 0.f;
  #pragma unroll
  for (int nt = 0; nt < 4; nt++) {
    #pragma unroll
    for (int i = 0; i < 4; i++) {
      const int n = nt * 16 + quad * 4 + i;
      float v0 = acch[nt][0][i], v1 = acch[nt][1][i];
      sm0 += v0; sq0 += v0 * v0;
      sm1 += v1; sq1 += v1 * v1;
      Hb[n * D_ + d0 + m]      = f2b(v0);
      Hb[n * D_ + d0 + 16 + m] = f2b(v1);
    }
  }
  sm0 += __shfl_xor(sm0, 16); sm0 += __shfl_xor(sm0, 32);
  sq0 += __shfl_xor(sq0, 16); sq0 += __shfl_xor(sq0, 32);
  sm1 += __shfl_xor(sm1, 16); sm1 += __shfl_xor(sm1, 32);
  sq1 += __shfl_xor(sq1, 16); sq1 += __shfl_xor(sq1, 32);
  if (quad == 0) {
    float* st = f + WS_STATS + (blockIdx.x & (NBKT - 1)) * 256;
    atomicAdd(&st[d0 + m], sm0);
    atomicAdd(&st[128 + d0 + m], sq0);
    atomicAdd(&st[d0 + 16 + m], sm1);
    atomicAdd(&st[128 + d0 + 16 + m], sq1);
  }
}

// K2: epilogue, register-resident: read H frags, BN+ReLU in-reg, GEMM2 + pred.
// grid 1024, 64 rows/block (4 x 16-row tiles), no z-LDS, no in-loop barriers.
__global__ __launch_bounds__(256) void kD(
    const float* __restrict__ gamma, const float* __restrict__ beta,
    const float* __restrict__ br, const float* __restrict__ wp,
    const float* __restrict__ bp, float* ws, float* __restrict__ out)
{
  __shared__ float rsL[D_], zbL[D_], wpL[D_];
  float* f = ws;
  const unsigned short* H   = (const unsigned short*)(f + WS_H);
  const unsigned short* wrT = (const unsigned short*)(f + WS_WRT);
  const int t = threadIdx.x;
  const int wv = t >> 6, lane = t & 63;
  const int m = lane & 15, quad = lane >> 4;
  const size_t row0 = (size_t)blockIdx.x * 64;

  if (t < 128) {
    float s = 0.f, sq = 0.f;
    #pragma unroll
    for (int bk = 0; bk < NBKT; bk++) {
      s  += f[WS_STATS + bk * 256 + t];
      sq += f[WS_STATS + bk * 256 + 128 + t];
    }
    float mu  = s * (1.f / (float)BN_);
    float var = sq * (1.f / (float)BN_) - mu * mu;
    float rg  = rsqrtf(var + EPS_) * gamma[t];
    rsL[t] = rg;
    zbL[t] = beta[t] - mu * rg;
    wpL[t] = wp[t];
  }
  // B-frags for GEMM2 (col = wv*16+m, fixed per lane), loaded once
  const int col = wv * 16 + m;
  bf16x8 bz[4];
  #pragma unroll
  for (int s = 0; s < 4; s++)
    bz[s] = *(const bf16x8*)(wrT + col * D_ + s * 32 + quad * 8);
  const float bias = br[col];
  const float bpv = bp[0];
  __syncthreads();

  #pragma unroll
  for (int rt = 0; rt < 4; rt++) {
    const size_t row = row0 + rt * 16 + m;      // this lane's H row
    float predp = 0.f;
    f32x4 acc2 = {bias, bias, bias, bias};
    #pragma unroll
    for (int s = 0; s < 4; s++) {
      const int cbase = s * 32 + quad * 8;
      bf16x8 h8 = *(const bf16x8*)(H + row * D_ + cbase);
      bf16x8 z8;
      #pragma unroll
      for (int j = 0; j < 8; j++) {
        const int c = cbase + j;
        float z = fmaf(b2f((unsigned short)h8[j]), rsL[c], zbL[c]);
        z = z > 0.f ? z : 0.f;
        predp += z * wpL[c];
        z8[j] = (short)f2b(z);
      }
      acc2 = __builtin_amdgcn_mfma_f32_16x16x32_bf16(z8, bz[s], acc2, 0, 0, 0);
    }
    // pred: combine the 4 quads holding row's 128 cols
    predp += __shfl_xor(predp, 16); predp += __shfl_xor(predp, 32);
    if (quad == 0) out[OFF_PRED + row] = predp + bpv;
    // recons: C-layout rows quad*4+i, col = wv*16+m
    #pragma unroll
    for (int i = 0; i < 4; i++)
      out[(row0 + rt * 16 + quad * 4 + i) * F_ + col] = acc2[i];
  }
}

extern "C" void kernel_launch(void* const* d_in, const int* in_sizes, int n_in,
                              void* d_out, int out_size, void* d_ws, size_t ws_size,
                              hipStream_t stream) {
  const float* data  = (const float*)d_in[0];
  const int*   ei    = (const int*)d_in[1];
  const float* W     = (const float*)d_in[2];
  const float* lin_w = (const float*)d_in[3];
  // d_in[4] = gnn_bias: cancels exactly through training-mode BN
  const float* gamma = (const float*)d_in[5];
  const float* beta  = (const float*)d_in[6];
  const float* Wr    = (const float*)d_in[7];
  const float* br    = (const float*)d_in[8];
  const float* wp    = (const float*)d_in[9];
  const float* bp    = (const float*)d_in[10];
  float* out = (float*)d_out;
  float* ws  = (float*)d_ws;
  unsigned short* outs = (unsigned short*)d_out;   // XT @0, A @A_U16 (scratch)

  k_prep <<<1856, 256, 0, stream>>>(data, W, lin_w, Wr, ei, ws, outs, out);
  kBC    <<<1024, 256, 0, stream>>>(outs, ws);
  kD     <<<1024, 256, 0, stream>>>(gamma, beta, br, wp, bp, ws, out);
}

// Round 9
// 136.478 us; speedup vs baseline: 1.2552x; 1.0264x over previous
//
#include <hip/hip_runtime.h>
#include <hip/hip_bf16.h>

constexpr int B_  = 128;
constexpr int N_  = 512;
constexpr int F_  = 64;
constexpr int D_  = 128;
constexpr int E_  = 8192;
constexpr int BN_ = B_ * N_;              // 65536
constexpr float SLOPE = 0.2f;
constexpr float EPS_  = 1e-5f;
constexpr int OFF_PRED = BN_ * F_;        // 4194304 (elements)
constexpr int OFF_W    = OFF_PRED + BN_;  // 4259840

// workspace float-offsets (ws = 256 MiB per the fillBuffer WRITE_SIZE)
constexpr int WS_STATS = 16896;    // f[16][256]  bucketed (sum | sumsq), 4096 floats
constexpr int NBKT     = 16;
constexpr int WS_WLT   = 25860;    // u16[128n][64k]   (bf16 Wl^T)
constexpr int WS_WRT   = 29956;    // u16[64n][128k]   (bf16 Wr^T)
constexpr int WS_H     = 34052;    // bf16[BN*136] = 17.8 MB (byte 136208, 16B aligned)
// H row stride PADDED to 136 u16 (272 B): breaks the 256B power-of-2 stride so
// kBC's 32B store segments and kD's 16-row read gathers spread across L2
// channels (same mechanism as the XT/A pad that fixed kBC in round 7).
constexpr int HP = 136;

// scratch carved out of `out` (fully overwritten later by kD's recons).
// Row strides PADDED to 544 u16 (1088 B): rows shift one 64B line each, so the
// 16-row gathers in kBC spread over 16 L2 channels instead of camping on 1-2.
constexpr int XTP   = 544;
constexpr int AP    = 544;
constexpr int A_U16 = B_ * F_ * XTP;      // 4,456,448

typedef __attribute__((ext_vector_type(8))) short bf16x8;
typedef __attribute__((ext_vector_type(4))) float f32x4;

__device__ __forceinline__ float lrelu(float w) { return w > 0.f ? w : SLOPE * w; }
__device__ __forceinline__ unsigned short f2b(float v) {
  __hip_bfloat16 h = __float2bfloat16(v);
  return *(unsigned short*)&h;
}
__device__ __forceinline__ float b2f(unsigned short u) {
  __hip_bfloat16 h = *(__hip_bfloat16*)&u;
  return __bfloat162float(h);
}

// K0: fused prep, grid 1856.
//   [   0,1024): XT[b][f][m] = bf16(X[b][m][f])  (block 0 zeros stat buckets)
//   [1024,1056): wlT[n][k] = bf16(Wl[k][n])
//   [1056,1088): wrT[n][k] = bf16(Wr[k][n])
//   [1088,1344): W passthrough copy (float4)
//   [1344,1856): dense softmax row build (one block per dst node)
__global__ __launch_bounds__(256) void k_prep(
    const float* __restrict__ X, const float* __restrict__ W,
    const float* __restrict__ Wl, const float* __restrict__ Wr,
    const int* __restrict__ ei,
    float* ws, unsigned short* __restrict__ outs, float* __restrict__ out)
{
  const int t = threadIdx.x;
  const int blk = blockIdx.x;
  if (blk < 1024) {
    if (blk == 0) {
      #pragma unroll
      for (int i = 0; i < NBKT; i++) ws[WS_STATS + i * 256 + t] = 0.f;
    }
    const int b  = blk >> 3;
    const int mh = blk & 1, fh = (blk >> 1) & 3;
    const int m  = (mh << 8) + t;
    const float* xrow = X + ((size_t)b * N_ + m) * F_ + fh * 16;
    unsigned short* xtb = outs + (size_t)b * (F_ * XTP) + fh * 16 * XTP;
    #pragma unroll
    for (int f4 = 0; f4 < 4; f4++) {
      float4 v = *(const float4*)(xrow + f4 * 4);
      xtb[(f4 * 4 + 0) * XTP + m] = f2b(v.x);
      xtb[(f4 * 4 + 1) * XTP + m] = f2b(v.y);
      xtb[(f4 * 4 + 2) * XTP + m] = f2b(v.z);
      xtb[(f4 * 4 + 3) * XTP + m] = f2b(v.w);
    }
  } else if (blk < 1056) {
    unsigned short* wlT = (unsigned short*)(ws + WS_WLT);
    int i = (blk - 1024) * 256 + t;           // [0, 8192)
    int n = i >> 6, k = i & 63;
    wlT[i] = f2b(Wl[k * D_ + n]);
  } else if (blk < 1088) {
    unsigned short* wrT = (unsigned short*)(ws + WS_WRT);
    int i = (blk - 1056) * 256 + t;           // [0, 8192)
    int n = i >> 7, k = i & 127;
    wrT[i] = f2b(Wr[k * F_ + n]);
  } else if (blk < 1344) {
    int i = (blk - 1088) * 256 + t;           // [0, 65536)
    ((float4*)(out + OFF_W))[i] = ((const float4*)W)[i];
  } else {
    // dense masked row softmax (exact duplicate handling: cnt * e^a)
    __shared__ unsigned cnt[N_];
    __shared__ float red[8];
    unsigned short* Abf = outs + A_U16;
    const int row = blk - 1344;
    const int wv = t >> 6;
    cnt[t] = 0u; cnt[t + 256] = 0u;
    __syncthreads();
    for (int e = t; e < E_; e += 256) {
      int d = ei[E_ + e];
      if (d == row) atomicAdd(&cnt[ei[e]], 1u);
    }
    __syncthreads();
    const int s0 = t, s1 = t + 256;
    const float a0 = lrelu(W[row * N_ + s0]);
    const float a1 = lrelu(W[row * N_ + s1]);
    const unsigned c0 = cnt[s0] + (s0 == row ? 1u : 0u);
    const unsigned c1 = cnt[s1] + (s1 == row ? 1u : 0u);
    float m = fmaxf(c0 ? a0 : -3.4e38f, c1 ? a1 : -3.4e38f);
    #pragma unroll
    for (int off = 32; off; off >>= 1) m = fmaxf(m, __shfl_xor(m, off));
    if ((t & 63) == 0) red[wv] = m;
    __syncthreads();
    const float amax = fmaxf(fmaxf(red[0], red[1]), fmaxf(red[2], red[3]));
    const float e0 = c0 ? (float)c0 * __expf(a0 - amax) : 0.f;
    const float e1 = c1 ? (float)c1 * __expf(a1 - amax) : 0.f;
    float sm = e0 + e1;
    #pragma unroll
    for (int off = 32; off; off >>= 1) sm += __shfl_xor(sm, off);
    if ((t & 63) == 0) red[4 + wv] = sm;
    __syncthreads();
    const float inv = 1.f / (red[4] + red[5] + red[6] + red[7]);
    Abf[row * AP + s0] = f2b(e0 * inv);
    Abf[row * AP + s1] = f2b(e1 * inv);
  }
}

// K1: aggregation + projection + BN stats; writes H (bf16, padded stride).
//   Y-tile (64n x 64f) = A-slice @ XT_b via MFMA -> swizzled ys LDS
//   h-tile (64n x 128d) = Y @ Wl via MFMA -> H global (from registers)
//   stats -> bucketed end-of-kernel atomics.
// grid = 1024: b = blk&127 (blocks sharing XT_b sit stride-128 => same XCD),
// ns = blk>>7 (8 slices of 64 rows). 4 waves; LDS = 8 KB.
__global__ __launch_bounds__(256, 4) void kBC(
    const unsigned short* __restrict__ XT, float* ws)
{
  __shared__ __align__(16) unsigned short ys[64 * 64];    // Y tile, XOR-swizzled
  float* f = ws;
  unsigned short* H = (unsigned short*)(ws + WS_H);
  const unsigned short* wlT = (const unsigned short*)(ws + WS_WLT);
  const unsigned short* Abf = XT + A_U16;
  const int t = threadIdx.x;
  const int wv = t >> 6, lane = t & 63;
  const int m = lane & 15, quad = lane >> 4;
  const int b = blockIdx.x & 127, ns = blockIdx.x >> 7;   // ns in [0,8)
  const int n0 = ns * 64;

  // ---- Y GEMM: Y^T[f][n] = XT_b[f][:] . A[n][:]; wave wv = f-rows [16wv,16wv+16) ----
  // unroll 8: widen the load-scheduling window so ~40 independent gathers can
  // be in flight (round-5 showed the compiler otherwise keeps VGPR use tiny).
  const unsigned short* af = XT + (size_t)b * (F_ * XTP) + (wv * 16 + m) * XTP;
  f32x4 acc[4] = {{0.f,0.f,0.f,0.f},{0.f,0.f,0.f,0.f},
                  {0.f,0.f,0.f,0.f},{0.f,0.f,0.f,0.f}};
  #pragma unroll 8
  for (int kk = 0; kk < 16; kk++) {
    const int k0 = kk * 32 + quad * 8;
    bf16x8 a = *(const bf16x8*)(af + k0);
    #pragma unroll
    for (int nt = 0; nt < 4; nt++) {
      bf16x8 bb = *(const bf16x8*)(Abf + (n0 + nt * 16 + m) * AP + k0);
      acc[nt] = __builtin_amdgcn_mfma_f32_16x16x32_bf16(a, bb, acc[nt], 0, 0, 0);
    }
  }
  // Y tile -> swizzled ys only (no global Y)
  #pragma unroll
  for (int nt = 0; nt < 4; nt++) {
    const int n = nt * 16 + m;
    const int c = (wv * 16 + quad * 4) ^ ((n & 7) << 3);
    ushort4 y4;
    y4.x = f2b(acc[nt][0]); y4.y = f2b(acc[nt][1]);
    y4.z = f2b(acc[nt][2]); y4.w = f2b(acc[nt][3]);
    *(ushort4*)(ys + n * 64 + c) = y4;
  }
  __syncthreads();

  // ---- h GEMM: wave wv owns d0 = wv*32 ----
  const int d0 = wv * 32;
  bf16x8 bw00 = *(const bf16x8*)(wlT + (d0 + m) * 64 + quad * 8);
  bf16x8 bw01 = *(const bf16x8*)(wlT + (d0 + m) * 64 + 32 + quad * 8);
  bf16x8 bw10 = *(const bf16x8*)(wlT + (d0 + 16 + m) * 64 + quad * 8);
  bf16x8 bw11 = *(const bf16x8*)(wlT + (d0 + 16 + m) * 64 + 32 + quad * 8);
  f32x4 acch[4][2];
  #pragma unroll
  for (int nt = 0; nt < 4; nt++) {
    acch[nt][0] = f32x4{0.f,0.f,0.f,0.f};
    acch[nt][1] = f32x4{0.f,0.f,0.f,0.f};
  }
  #pragma unroll
  for (int nt = 0; nt < 4; nt++) {
    const int n2 = nt * 16 + m;
    const int sw = (n2 & 7) << 3;
    bf16x8 aA = *(const bf16x8*)(ys + n2 * 64 + ((quad * 8) ^ sw));
    bf16x8 aB = *(const bf16x8*)(ys + n2 * 64 + ((32 + quad * 8) ^ sw));
    acch[nt][0] = __builtin_amdgcn_mfma_f32_16x16x32_bf16(aA, bw00, acch[nt][0], 0, 0, 0);
    acch[nt][0] = __builtin_amdgcn_mfma_f32_16x16x32_bf16(aB, bw01, acch[nt][0], 0, 0, 0);
    acch[nt][1] = __builtin_amdgcn_mfma_f32_16x16x32_bf16(aA, bw10, acch[nt][1], 0, 0, 0);
    acch[nt][1] = __builtin_amdgcn_mfma_f32_16x16x32_bf16(aB, bw11, acch[nt][1], 0, 0, 0);
  }

  // ---- H store (bf16, padded stride) + stat accumulation ----
  unsigned short* Hb = H + ((size_t)b * N_ + n0) * HP;
  float sm0 = 0.f, sq0 = 0.f, sm1 = 0.f, sq1 = 0.f;
  #pragma unroll
  for (int nt = 0; nt < 4; nt++) {
    #pragma unroll
    for (int i = 0; i < 4; i++) {
      const int n = nt * 16 + quad * 4 + i;
      float v0 = acch[nt][0][i], v1 = acch[nt][1][i];
      sm0 += v0; sq0 += v0 * v0;
      sm1 += v1; sq1 += v1 * v1;
      Hb[n * HP + d0 + m]      = f2b(v0);
      Hb[n * HP + d0 + 16 + m] = f2b(v1);
    }
  }
  sm0 += __shfl_xor(sm0, 16); sm0 += __shfl_xor(sm0, 32);
  sq0 += __shfl_xor(sq0, 16); sq0 += __shfl_xor(sq0, 32);
  sm1 += __shfl_xor(sm1, 16); sm1 += __shfl_xor(sm1, 32);
  sq1 += __shfl_xor(sq1, 16); sq1 += __shfl_xor(sq1, 32);
  if (quad == 0) {
    float* st = f + WS_STATS + (blockIdx.x & (NBKT - 1)) * 256;
    atomicAdd(&st[d0 + m], sm0);
    atomicAdd(&st[128 + d0 + m], sq0);
    atomicAdd(&st[d0 + 16 + m], sm1);
    atomicAdd(&st[128 + d0 + 16 + m], sq1);
  }
}

// K2: epilogue, register-resident: read H frags, BN+ReLU in-reg, GEMM2 + pred.
// grid 512, 128 rows/block (8 x 16-row tiles), no z-LDS, no in-loop barriers.
__global__ __launch_bounds__(256) void kD(
    const float* __restrict__ gamma, const float* __restrict__ beta,
    const float* __restrict__ br, const float* __restrict__ wp,
    const float* __restrict__ bp, float* ws, float* __restrict__ out)
{
  __shared__ float rsL[D_], zbL[D_], wpL[D_];
  float* f = ws;
  const unsigned short* H   = (const unsigned short*)(f + WS_H);
  const unsigned short* wrT = (const unsigned short*)(f + WS_WRT);
  const int t = threadIdx.x;
  const int wv = t >> 6, lane = t & 63;
  const int m = lane & 15, quad = lane >> 4;
  const size_t row0 = (size_t)blockIdx.x * 128;

  if (t < 128) {
    float s = 0.f, sq = 0.f;
    #pragma unroll
    for (int bk = 0; bk < NBKT; bk++) {
      s  += f[WS_STATS + bk * 256 + t];
      sq += f[WS_STATS + bk * 256 + 128 + t];
    }
    float mu  = s * (1.f / (float)BN_);
    float var = sq * (1.f / (float)BN_) - mu * mu;
    float rg  = rsqrtf(var + EPS_) * gamma[t];
    rsL[t] = rg;
    zbL[t] = beta[t] - mu * rg;
    wpL[t] = wp[t];
  }
  // B-frags for GEMM2 (col = wv*16+m, fixed per lane), loaded once
  const int col = wv * 16 + m;
  bf16x8 bz[4];
  #pragma unroll
  for (int s = 0; s < 4; s++)
    bz[s] = *(const bf16x8*)(wrT + col * D_ + s * 32 + quad * 8);
  const float bias = br[col];
  const float bpv = bp[0];
  __syncthreads();

  #pragma unroll
  for (int rt = 0; rt < 8; rt++) {
    const size_t row = row0 + rt * 16 + m;      // this lane's H row
    float predp = 0.f;
    f32x4 acc2 = {bias, bias, bias, bias};
    #pragma unroll
    for (int s = 0; s < 4; s++) {
      const int cbase = s * 32 + quad * 8;
      bf16x8 h8 = *(const bf16x8*)(H + row * HP + cbase);
      bf16x8 z8;
      #pragma unroll
      for (int j = 0; j < 8; j++) {
        const int c = cbase + j;
        float z = fmaf(b2f((unsigned short)h8[j]), rsL[c], zbL[c]);
        z = z > 0.f ? z : 0.f;
        predp += z * wpL[c];
        z8[j] = (short)f2b(z);
      }
      acc2 = __builtin_amdgcn_mfma_f32_16x16x32_bf16(z8, bz[s], acc2, 0, 0, 0);
    }
    // pred: combine the 4 quads holding row's 128 cols
    predp += __shfl_xor(predp, 16); predp += __shfl_xor(predp, 32);
    if (quad == 0) out[OFF_PRED + row] = predp + bpv;
    // recons: C-layout rows quad*4+i, col = wv*16+m
    #pragma unroll
    for (int i = 0; i < 4; i++)
      out[(row0 + rt * 16 + quad * 4 + i) * F_ + col] = acc2[i];
  }
}

extern "C" void kernel_launch(void* const* d_in, const int* in_sizes, int n_in,
                              void* d_out, int out_size, void* d_ws, size_t ws_size,
                              hipStream_t stream) {
  const float* data  = (const float*)d_in[0];
  const int*   ei    = (const int*)d_in[1];
  const float* W     = (const float*)d_in[2];
  const float* lin_w = (const float*)d_in[3];
  // d_in[4] = gnn_bias: cancels exactly through training-mode BN
  const float* gamma = (const float*)d_in[5];
  const float* beta  = (const float*)d_in[6];
  const float* Wr    = (const float*)d_in[7];
  const float* br    = (const float*)d_in[8];
  const float* wp    = (const float*)d_in[9];
  const float* bp    = (const float*)d_in[10];
  float* out = (float*)d_out;
  float* ws  = (float*)d_ws;
  unsigned short* outs = (unsigned short*)d_out;   // XT @0, A @A_U16 (scratch)

  k_prep <<<1856, 256, 0, stream>>>(data, W, lin_w, Wr, ei, ws, outs, out);
  kBC    <<<1024, 256, 0, stream>>>(outs, ws);
  kD     <<<512,  256, 0, stream>>>(gamma, beta, br, wp, bp, ws, out);
}

// Round 10
// 129.310 us; speedup vs baseline: 1.3248x; 1.0554x over previous
//
#include <hip/hip_runtime.h>
#include <hip/hip_bf16.h>

constexpr int B_  = 128;
constexpr int N_  = 512;
constexpr int F_  = 64;
constexpr int D_  = 128;
constexpr int E_  = 8192;
constexpr int BN_ = B_ * N_;              // 65536
constexpr float SLOPE = 0.2f;
constexpr float EPS_  = 1e-5f;
constexpr int OFF_PRED = BN_ * F_;        // 4194304 (elements)
constexpr int OFF_W    = OFF_PRED + BN_;  // 4259840

// workspace float-offsets (ws = 256 MiB per the fillBuffer WRITE_SIZE)
constexpr int WS_STATS = 16896;    // f[16][256]  bucketed (sum | sumsq), 4096 floats
constexpr int NBKT     = 16;
constexpr int WS_WLT   = 25860;    // u16[128n][64k]   (bf16 Wl^T)
constexpr int WS_WRT   = 29956;    // u16[64n][128k]   (bf16 Wr^T)
constexpr int WS_H     = 34052;    // Hf bf16, 16.7MB (byte 136208, 16B aligned)
// H is stored in MFMA A-FRAGMENT layout: Hf[rblk][s][lane][8] u16 where
// rblk = row>>4, s = col>>5, lane = ((col>>3)&3)*16 + (row&15), j = col&7.
// kD's per-(rt,s) load is then 64 lanes x 16B CONSECUTIVE (1KB streaming)
// instead of a 16-row x 272B-stride gather.

// scratch carved out of `out` (fully overwritten later by kD's recons).
// Row strides PADDED to 544 u16 (1088 B): rows shift one 64B line each, so
// 16-row gathers spread over 16 L2 channels instead of camping on 1-2.
constexpr int XTP   = 544;
constexpr int AP    = 544;
constexpr int A_U16 = B_ * F_ * XTP;      // 4,456,448

typedef __attribute__((ext_vector_type(8))) short bf16x8;
typedef __attribute__((ext_vector_type(4))) float f32x4;

__device__ __forceinline__ float lrelu(float w) { return w > 0.f ? w : SLOPE * w; }
__device__ __forceinline__ unsigned short f2b(float v) {
  __hip_bfloat16 h = __float2bfloat16(v);
  return *(unsigned short*)&h;
}
__device__ __forceinline__ float b2f(unsigned short u) {
  __hip_bfloat16 h = *(__hip_bfloat16*)&u;
  return __bfloat162float(h);
}

// K0: fused prep, grid 1856.  (unchanged from round 9)
__global__ __launch_bounds__(256) void k_prep(
    const float* __restrict__ X, const float* __restrict__ W,
    const float* __restrict__ Wl, const float* __restrict__ Wr,
    const int* __restrict__ ei,
    float* ws, unsigned short* __restrict__ outs, float* __restrict__ out)
{
  const int t = threadIdx.x;
  const int blk = blockIdx.x;
  if (blk < 1024) {
    if (blk == 0) {
      #pragma unroll
      for (int i = 0; i < NBKT; i++) ws[WS_STATS + i * 256 + t] = 0.f;
    }
    const int b  = blk >> 3;
    const int mh = blk & 1, fh = (blk >> 1) & 3;
    const int m  = (mh << 8) + t;
    const float* xrow = X + ((size_t)b * N_ + m) * F_ + fh * 16;
    unsigned short* xtb = outs + (size_t)b * (F_ * XTP) + fh * 16 * XTP;
    #pragma unroll
    for (int f4 = 0; f4 < 4; f4++) {
      float4 v = *(const float4*)(xrow + f4 * 4);
      xtb[(f4 * 4 + 0) * XTP + m] = f2b(v.x);
      xtb[(f4 * 4 + 1) * XTP + m] = f2b(v.y);
      xtb[(f4 * 4 + 2) * XTP + m] = f2b(v.z);
      xtb[(f4 * 4 + 3) * XTP + m] = f2b(v.w);
    }
  } else if (blk < 1056) {
    unsigned short* wlT = (unsigned short*)(ws + WS_WLT);
    int i = (blk - 1024) * 256 + t;           // [0, 8192)
    int n = i >> 6, k = i & 63;
    wlT[i] = f2b(Wl[k * D_ + n]);
  } else if (blk < 1088) {
    unsigned short* wrT = (unsigned short*)(ws + WS_WRT);
    int i = (blk - 1056) * 256 + t;           // [0, 8192)
    int n = i >> 7, k = i & 127;
    wrT[i] = f2b(Wr[k * F_ + n]);
  } else if (blk < 1344) {
    int i = (blk - 1088) * 256 + t;           // [0, 65536)
    ((float4*)(out + OFF_W))[i] = ((const float4*)W)[i];
  } else {
    // dense masked row softmax (exact duplicate handling: cnt * e^a)
    __shared__ unsigned cnt[N_];
    __shared__ float red[8];
    unsigned short* Abf = outs + A_U16;
    const int row = blk - 1344;
    const int wv = t >> 6;
    cnt[t] = 0u; cnt[t + 256] = 0u;
    __syncthreads();
    for (int e = t; e < E_; e += 256) {
      int d = ei[E_ + e];
      if (d == row) atomicAdd(&cnt[ei[e]], 1u);
    }
    __syncthreads();
    const int s0 = t, s1 = t + 256;
    const float a0 = lrelu(W[row * N_ + s0]);
    const float a1 = lrelu(W[row * N_ + s1]);
    const unsigned c0 = cnt[s0] + (s0 == row ? 1u : 0u);
    const unsigned c1 = cnt[s1] + (s1 == row ? 1u : 0u);
    float m = fmaxf(c0 ? a0 : -3.4e38f, c1 ? a1 : -3.4e38f);
    #pragma unroll
    for (int off = 32; off; off >>= 1) m = fmaxf(m, __shfl_xor(m, off));
    if ((t & 63) == 0) red[wv] = m;
    __syncthreads();
    const float amax = fmaxf(fmaxf(red[0], red[1]), fmaxf(red[2], red[3]));
    const float e0 = c0 ? (float)c0 * __expf(a0 - amax) : 0.f;
    const float e1 = c1 ? (float)c1 * __expf(a1 - amax) : 0.f;
    float sm = e0 + e1;
    #pragma unroll
    for (int off = 32; off; off >>= 1) sm += __shfl_xor(sm, off);
    if ((t & 63) == 0) red[4 + wv] = sm;
    __syncthreads();
    const float inv = 1.f / (red[4] + red[5] + red[6] + red[7]);
    Abf[row * AP + s0] = f2b(e0 * inv);
    Abf[row * AP + s1] = f2b(e1 * inv);
  }
}

// K1: aggregation + projection + BN stats; A LDS-staged; writes Hf layout.
//   Per K-chunk (128): stage A[64n][128k] coalesced into swizzled LDS (read
//   ONCE per block instead of once per wave = 4x L2 relief), then MFMA with
//   bb from conflict-free ds_read_b128.
// grid = 1024: b = blk&127 (blocks sharing XT_b sit stride-128 => same XCD),
// ns = blk>>7 (8 slices of 64 rows). 4 waves; LDS = 24 KB.
__global__ __launch_bounds__(256, 4) void kBC(
    const unsigned short* __restrict__ XT, float* ws)
{
  __shared__ __align__(16) unsigned short As[64 * 128];   // A K-chunk, swizzled
  __shared__ __align__(16) unsigned short ys[64 * 64];    // Y tile, XOR-swizzled
  float* f = ws;
  unsigned short* H = (unsigned short*)(ws + WS_H);
  const unsigned short* wlT = (const unsigned short*)(ws + WS_WLT);
  const unsigned short* Abf = XT + A_U16;
  const int t = threadIdx.x;
  const int wv = t >> 6, lane = t & 63;
  const int m = lane & 15, quad = lane >> 4;
  const int b = blockIdx.x & 127, ns = blockIdx.x >> 7;   // ns in [0,8)
  const int n0 = ns * 64;

  // ---- Y GEMM: Y^T[f][n] = XT_b[f][:] . A[n][:]; wave wv = f-rows [16wv,16wv+16) ----
  const unsigned short* af = XT + (size_t)b * (F_ * XTP) + (wv * 16 + m) * XTP;
  const int srow = wv * 4 + (lane >> 4);    // stage: 4 rows/wave (+16p)
  const int sg   = lane & 15;               // 16B granule within 256B chunk
  f32x4 acc[4] = {{0.f,0.f,0.f,0.f},{0.f,0.f,0.f,0.f},
                  {0.f,0.f,0.f,0.f},{0.f,0.f,0.f,0.f}};
  for (int kc = 0; kc < 4; kc++) {
    // stage A chunk [64 rows][128 u16]: coalesced 256B segments, XOR-swizzled
    #pragma unroll
    for (int p = 0; p < 4; p++) {
      const int rr = srow + 16 * p;
      bf16x8 v = *(const bf16x8*)(Abf + (n0 + rr) * AP + kc * 128 + sg * 8);
      *(bf16x8*)(As + rr * 128 + ((sg ^ (rr & 7)) << 3)) = v;
    }
    __syncthreads();
    #pragma unroll
    for (int kk = 0; kk < 4; kk++) {
      const int k0 = kc * 128 + kk * 32 + quad * 8;
      bf16x8 a = *(const bf16x8*)(af + k0);
      #pragma unroll
      for (int nt = 0; nt < 4; nt++) {
        const int n2 = nt * 16 + m;
        bf16x8 bb = *(const bf16x8*)(As + n2 * 128 +
                                     ((((kk << 2) + quad) ^ (n2 & 7)) << 3));
        acc[nt] = __builtin_amdgcn_mfma_f32_16x16x32_bf16(a, bb, acc[nt], 0, 0, 0);
      }
    }
    __syncthreads();
  }
  // Y tile -> swizzled ys
  #pragma unroll
  for (int nt = 0; nt < 4; nt++) {
    const int n = nt * 16 + m;
    const int c = (wv * 16 + quad * 4) ^ ((n & 7) << 3);
    ushort4 y4;
    y4.x = f2b(acc[nt][0]); y4.y = f2b(acc[nt][1]);
    y4.z = f2b(acc[nt][2]); y4.w = f2b(acc[nt][3]);
    *(ushort4*)(ys + n * 64 + c) = y4;
  }
  __syncthreads();

  // ---- h GEMM: wave wv owns d0 = wv*32 ----
  const int d0 = wv * 32;
  bf16x8 bw00 = *(const bf16x8*)(wlT + (d0 + m) * 64 + quad * 8);
  bf16x8 bw01 = *(const bf16x8*)(wlT + (d0 + m) * 64 + 32 + quad * 8);
  bf16x8 bw10 = *(const bf16x8*)(wlT + (d0 + 16 + m) * 64 + quad * 8);
  bf16x8 bw11 = *(const bf16x8*)(wlT + (d0 + 16 + m) * 64 + 32 + quad * 8);
  f32x4 acch[4][2];
  #pragma unroll
  for (int nt = 0; nt < 4; nt++) {
    acch[nt][0] = f32x4{0.f,0.f,0.f,0.f};
    acch[nt][1] = f32x4{0.f,0.f,0.f,0.f};
  }
  #pragma unroll
  for (int nt = 0; nt < 4; nt++) {
    const int n2 = nt * 16 + m;
    const int sw = (n2 & 7) << 3;
    bf16x8 aA = *(const bf16x8*)(ys + n2 * 64 + ((quad * 8) ^ sw));
    bf16x8 aB = *(const bf16x8*)(ys + n2 * 64 + ((32 + quad * 8) ^ sw));
    acch[nt][0] = __builtin_amdgcn_mfma_f32_16x16x32_bf16(aA, bw00, acch[nt][0], 0, 0, 0);
    acch[nt][0] = __builtin_amdgcn_mfma_f32_16x16x32_bf16(aB, bw01, acch[nt][0], 0, 0, 0);
    acch[nt][1] = __builtin_amdgcn_mfma_f32_16x16x32_bf16(aA, bw10, acch[nt][1], 0, 0, 0);
    acch[nt][1] = __builtin_amdgcn_mfma_f32_16x16x32_bf16(aB, bw11, acch[nt][1], 0, 0, 0);
  }

  // ---- Hf store (fragment layout) + stat accumulation ----
  // element (r=b*512+n0+nt*16+quad*4+i, c=wv*32+dt*16+m) lives at
  // ((rblk*4 + wv)*64 + (dt*2+(m>>3))*16 + quad*4 + i)*8 + (m&7)
  const int lhi = m >> 3, jlo = m & 7;
  float sm0 = 0.f, sq0 = 0.f, sm1 = 0.f, sq1 = 0.f;
  #pragma unroll
  for (int nt = 0; nt < 4; nt++) {
    unsigned short* hb = H + ((size_t)((b * 32 + ns * 4 + nt) * 4 + wv)) * 512;
    #pragma unroll
    for (int i = 0; i < 4; i++) {
      float v0 = acch[nt][0][i], v1 = acch[nt][1][i];
      sm0 += v0; sq0 += v0 * v0;
      sm1 += v1; sq1 += v1 * v1;
      hb[((0 + lhi) * 16 + quad * 4 + i) * 8 + jlo] = f2b(v0);
      hb[((2 + lhi) * 16 + quad * 4 + i) * 8 + jlo] = f2b(v1);
    }
  }
  sm0 += __shfl_xor(sm0, 16); sm0 += __shfl_xor(sm0, 32);
  sq0 += __shfl_xor(sq0, 16); sq0 += __shfl_xor(sq0, 32);
  sm1 += __shfl_xor(sm1, 16); sm1 += __shfl_xor(sm1, 32);
  sq1 += __shfl_xor(sq1, 16); sq1 += __shfl_xor(sq1, 32);
  if (quad == 0) {
    float* st = f + WS_STATS + (blockIdx.x & (NBKT - 1)) * 256;
    atomicAdd(&st[d0 + m], sm0);
    atomicAdd(&st[128 + d0 + m], sq0);
    atomicAdd(&st[d0 + 16 + m], sm1);
    atomicAdd(&st[128 + d0 + 16 + m], sq1);
  }
}

// K2: epilogue, register-resident: Hf frag reads (1KB streaming per instr),
// BN+ReLU in-reg, GEMM2 + pred. grid 512, 128 rows/block (8 rblks).
__global__ __launch_bounds__(256) void kD(
    const float* __restrict__ gamma, const float* __restrict__ beta,
    const float* __restrict__ br, const float* __restrict__ wp,
    const float* __restrict__ bp, float* ws, float* __restrict__ out)
{
  __shared__ float rsL[D_], zbL[D_], wpL[D_];
  float* f = ws;
  const unsigned short* H   = (const unsigned short*)(f + WS_H);
  const unsigned short* wrT = (const unsigned short*)(f + WS_WRT);
  const int t = threadIdx.x;
  const int wv = t >> 6, lane = t & 63;
  const int m = lane & 15, quad = lane >> 4;
  const size_t row0 = (size_t)blockIdx.x * 128;
  const size_t rblk0 = (size_t)blockIdx.x * 8;

  if (t < 128) {
    float s = 0.f, sq = 0.f;
    #pragma unroll
    for (int bk = 0; bk < NBKT; bk++) {
      s  += f[WS_STATS + bk * 256 + t];
      sq += f[WS_STATS + bk * 256 + 128 + t];
    }
    float mu  = s * (1.f / (float)BN_);
    float var = sq * (1.f / (float)BN_) - mu * mu;
    float rg  = rsqrtf(var + EPS_) * gamma[t];
    rsL[t] = rg;
    zbL[t] = beta[t] - mu * rg;
    wpL[t] = wp[t];
  }
  // B-frags for GEMM2 (col = wv*16+m, fixed per lane), loaded once
  const int col = wv * 16 + m;
  bf16x8 bz[4];
  #pragma unroll
  for (int s = 0; s < 4; s++)
    bz[s] = *(const bf16x8*)(wrT + col * D_ + s * 32 + quad * 8);
  const float bias = br[col];
  const float bpv = bp[0];
  __syncthreads();

  #pragma unroll
  for (int rt = 0; rt < 8; rt++) {
    const size_t row = row0 + rt * 16 + m;      // this lane's logical H row
    float predp = 0.f;
    f32x4 acc2 = {bias, bias, bias, bias};
    #pragma unroll
    for (int s = 0; s < 4; s++) {
      const int cbase = s * 32 + quad * 8;
      // Hf: wave reads lanes 0..63 consecutive -> 1KB contiguous
      bf16x8 h8 = *(const bf16x8*)(H + (((rblk0 + rt) * 4 + s) * 64 + lane) * 8);
      bf16x8 z8;
      #pragma unroll
      for (int j = 0; j < 8; j++) {
        const int c = cbase + j;
        float z = fmaf(b2f((unsigned short)h8[j]), rsL[c], zbL[c]);
        z = z > 0.f ? z : 0.f;
        predp += z * wpL[c];
        z8[j] = (short)f2b(z);
      }
      acc2 = __builtin_amdgcn_mfma_f32_16x16x32_bf16(z8, bz[s], acc2, 0, 0, 0);
    }
    // pred: combine the 4 quads holding row's 128 cols
    predp += __shfl_xor(predp, 16); predp += __shfl_xor(predp, 32);
    if (quad == 0) out[OFF_PRED + row] = predp + bpv;
    // recons: C-layout rows quad*4+i, col = wv*16+m
    #pragma unroll
    for (int i = 0; i < 4; i++)
      out[(row0 + rt * 16 + quad * 4 + i) * F_ + col] = acc2[i];
  }
}

extern "C" void kernel_launch(void* const* d_in, const int* in_sizes, int n_in,
                              void* d_out, int out_size, void* d_ws, size_t ws_size,
                              hipStream_t stream) {
  const float* data  = (const float*)d_in[0];
  const int*   ei    = (const int*)d_in[1];
  const float* W     = (const float*)d_in[2];
  const float* lin_w = (const float*)d_in[3];
  // d_in[4] = gnn_bias: cancels exactly through training-mode BN
  const float* gamma = (const float*)d_in[5];
  const float* beta  = (const float*)d_in[6];
  const float* Wr    = (const float*)d_in[7];
  const float* br    = (const float*)d_in[8];
  const float* wp    = (const float*)d_in[9];
  const float* bp    = (const float*)d_in[10];
  float* out = (float*)d_out;
  float* ws  = (float*)d_ws;
  unsigned short* outs = (unsigned short*)d_out;   // XT @0, A @A_U16 (scratch)

  k_prep <<<1856, 256, 0, stream>>>(data, W, lin_w, Wr, ei, ws, outs, out);
  kBC    <<<1024, 256, 0, stream>>>(outs, ws);
  kD     <<<512,  256, 0, stream>>>(gamma, beta, br, wp, bp, ws, out);
}